// Round 2
// baseline (172.510 us; speedup 1.0000x reference)
//
#include <hip/hip_runtime.h>

// FusionLoss: scalar loss.
// Inputs: output f32[128,16,128,128], mask i32[128,16], ind i32[128,16],
//         target f32[128,16,1], gt_2d f32[128,32].  Output: scalar f32.
//
// Structure: single block, 1024 threads. 8 threads per batch; each thread
// gathers 2 pred values (so all 2048 scattered loads are in flight from 16
// waves). pred staged via LDS (stride 17 to dodge bank conflicts); one
// thread per batch computes the 12-edge variance loss; block tree-reduce.

#define NJ 16
#define NE 12
#define NG 4
#define LDSS 17   // LDS row stride (16 + 1 pad)

__global__ __launch_bounds__(1024) void fusion_loss_kernel(
    const float* __restrict__ output,
    const int*   __restrict__ mask,
    const int*   __restrict__ ind,
    const float* __restrict__ target,
    const float* __restrict__ gt2d,
    float*       __restrict__ out)
{
    const int tid = threadIdx.x;
    const int b   = tid >> 3;     // batch 0..127
    const int sub = tid & 7;      // 0..7

    __shared__ float s_pred[128 * LDSS];
    __shared__ float s_red[16][3];

    const int j0 = sub, j1 = sub + 8;

    // ---- issue all loads up front ----
    const int t0 = ind[b * NJ + j0];
    const int t1 = ind[b * NJ + j1];
    const float v0 = target[b * NJ + j0];
    const float v1 = target[b * NJ + j1];
    const int   m0 = mask[b * NJ + j0];
    const int   m1 = mask[b * NJ + j1];

    // var-loss thread's dense per-batch loads, issued before the barrier so
    // their latency overlaps the gather round
    float tg[NJ]; int mk[NJ]; float g2[2 * NJ];
    if (sub == 0) {
        const float4* tp = (const float4*)(target + b * NJ);      // 64B aligned
        const int4*   mp = (const int4*)  (mask   + b * NJ);
        const float4* gp = (const float4*)(gt2d   + b * 2 * NJ);  // 128B aligned
#pragma unroll
        for (int k = 0; k < 4; ++k) {
            float4 tv = tp[k];
            tg[4*k] = tv.x; tg[4*k+1] = tv.y; tg[4*k+2] = tv.z; tg[4*k+3] = tv.w;
            int4 mv = mp[k];
            mk[4*k] = mv.x; mk[4*k+1] = mv.y; mk[4*k+2] = mv.z; mk[4*k+3] = mv.w;
        }
#pragma unroll
        for (int k = 0; k < 8; ++k) {
            float4 gv = gp[k];
            g2[4*k] = gv.x; g2[4*k+1] = gv.y; g2[4*k+2] = gv.z; g2[4*k+3] = gv.w;
        }
    }

    // gather: feat layout is h*(W*J) + w*J + j  ->  j = t&15, hw = t>>4
    const float* ob = output + (size_t)b * (NJ * 128 * 128);
    const float p0 = ob[(t0 & (NJ - 1)) * (128 * 128) + (t0 >> 4)];
    const float p1 = ob[(t1 & (NJ - 1)) * (128 * 128) + (t1 >> 4)];
    s_pred[b * LDSS + j0] = p0;
    s_pred[b * LDSS + j1] = p1;

    // ---- reg-loss partials (2 j's per thread) ----
    float sl1 = 0.0f, numm = 0.0f;
    {
        float m = (float)m0, d = p0 * m - v0 * m, ad = fabsf(d);
        sl1 += (ad < 1.0f) ? 0.5f * d * d : ad - 0.5f;  numm += m;
        m = (float)m1; d = p1 * m - v1 * m; ad = fabsf(d);
        sl1 += (ad < 1.0f) ? 0.5f * d * d : ad - 0.5f;  numm += m;
    }

    __syncthreads();

    // ---- var loss: one thread per batch, 12 edges in registers ----
    float tot = 0.0f;
    if (sub == 0) {
        const int   id1[NE] = {0,1,3,4,10,11,13,14,2,3,12,13};
        const int   id2[NE] = {1,2,4,5,11,12,14,15,6,6,8,8};
        const int   gid[NE] = {0,0,0,0,1,1,1,1,2,2,3,3};
        const float wsk[NE] = {1.0085885098415446f, 1.0f, 1.0f, 1.0085885098415446f,
                               1.1375361376887123f, 1.0f, 1.0f, 1.1375361376887123f,
                               1.0f, 1.0f, 1.0f, 1.0f};
        float pr[NJ];
#pragma unroll
        for (int j = 0; j < NJ; ++j) pr[j] = s_pred[b * LDSS + j];

        float gnum[NG] = {0.f,0.f,0.f,0.f};
        float gsum[NG] = {0.f,0.f,0.f,0.f};
        float lv[NE]; bool vvv[NE];
#pragma unroll
        for (int e = 0; e < NE; ++e) {
            const int a = id1[e], c = id2[e];
            const bool v = (tg[a] > 0.5f) && (tg[c] > 0.5f);
            float dx = g2[2*a] - g2[2*c];
            float dy = g2[2*a+1] - g2[2*c+1];
            float d2d = dx * dx + dy * dy;
            float dz  = pr[a] - pr[c];
            float s   = v ? (d2d + dz * dz) : 1.0f;
            float l   = v ? sqrtf(s) * wsk[e] : 0.0f;
            lv[e] = l; vvv[e] = v;
            gnum[gid[e]] += v ? 1.0f : 0.0f;
            gsum[gid[e]] += l;
        }
        float E[NG];
#pragma unroll
        for (int g = 0; g < NG; ++g)
            E[g] = (gnum[g] >= 0.5f) ? gsum[g] / fmaxf(gnum[g], 1.0f) : 0.0f;
#pragma unroll
        for (int e = 0; e < NE; ++e) {
            if (vvv[e]) {
                float ne = fmaxf(gnum[gid[e]], 1.0f);
                float dd = lv[e] - E[gid[e]];
                tot += dd * dd / (2.0f * ne);
            }
        }
        int msum = 0;
#pragma unroll
        for (int j = 0; j < NJ; ++j) msum += mk[j];
        if (msum != 0) tot = 0.0f;
    }

    // ---- block reduction: wave shuffle, then LDS across 16 waves ----
#pragma unroll
    for (int off = 32; off > 0; off >>= 1) {
        sl1  += __shfl_down(sl1,  off, 64);
        numm += __shfl_down(numm, off, 64);
        tot  += __shfl_down(tot,  off, 64);
    }
    const int wave = tid >> 6, lane = tid & 63;
    if (lane == 0) { s_red[wave][0] = sl1; s_red[wave][1] = numm; s_red[wave][2] = tot; }
    __syncthreads();
    if (tid == 0) {
        float S = 0.f, N = 0.f, T = 0.f;
#pragma unroll
        for (int w = 0; w < 16; ++w) { S += s_red[w][0]; N += s_red[w][1]; T += s_red[w][2]; }
        out[0] = S / (N + 0.0001f) + 0.01f * T / 128.0f;
    }
}

extern "C" void kernel_launch(void* const* d_in, const int* in_sizes, int n_in,
                              void* d_out, int out_size, void* d_ws, size_t ws_size,
                              hipStream_t stream) {
    const float* output = (const float*)d_in[0];
    const int*   mask   = (const int*)  d_in[1];
    const int*   ind    = (const int*)  d_in[2];
    const float* target = (const float*)d_in[3];
    const float* gt2d   = (const float*)d_in[4];
    float*       out    = (float*)d_out;

    fusion_loss_kernel<<<1, 1024, 0, stream>>>(output, mask, ind, target, gt2d, out);
}